// Round 7
// baseline (183.592 us; speedup 1.0000x reference)
//
#include <hip/hip_runtime.h>
#include <hip/hip_bf16.h>
#include <stdint.h>

#define C_IN  256
#define C_OUT 256
#define H_IN  224
#define W_IN  224
#define HP    226
#define WP    226
#define NPIX  (H_IN * W_IN)   // 50176 = 392 * 128
#define BM    128
#define BN    128
#define BK    64              // 128 B rows -> XOR-(row&7) swizzle, 0 conflicts (r2/r5 empirics)

typedef __attribute__((ext_vector_type(8))) short short8;
typedef __attribute__((ext_vector_type(4))) float f32x4;

__device__ __forceinline__ unsigned short f2bf(float f) {
    __hip_bfloat16 b = __float2bfloat16(f);
    return *(unsigned short*)&b;
}

// async global->LDS, 16B per lane; LDS dest is wave-uniform base + lane*16
__device__ __forceinline__ void gl_lds16(const unsigned short* g, unsigned short* l) {
    __builtin_amdgcn_global_load_lds(
        (const __attribute__((address_space(1))) unsigned int*)g,
        (__attribute__((address_space(3))) unsigned int*)l,
        16, 0, 0);
}

// ---------- prep kernels ----------

// merged: blocks [0,2304) do W transform; [2304, 2304+113) zero xp's pad border
__global__ void prep_misc(const float* __restrict__ wk, unsigned short* __restrict__ wb,
                          unsigned short* __restrict__ xp) {
    int b = blockIdx.x;
    if (b < 2304) {
        int idx = b * 256 + threadIdx.x;              // 9*256*256 total
        int c = idx & 255, o = (idx >> 8) & 255, p = idx >> 16;
        wb[((size_t)p * 256 + o) * 256 + c] = f2bf(wk[((size_t)o * 256 + c) * 9 + p]);
        return;
    }
    int i = (b - 2304) * 256 + threadIdx.x;           // uint4 index
    uint4 z = make_uint4(0u, 0u, 0u, 0u);
    if (i < 7232) {                                    // h = 0 row
        ((uint4*)xp)[i] = z;
    } else if (i < 14464) {                            // h = 225 row
        ((uint4*)(xp + (size_t)225 * WP * C_IN))[i - 7232] = z;
    } else if (i < 21632) {                            // w = 0 col, h 1..224
        int j = i - 14464; int h = 1 + (j >> 5); int c4 = j & 31;
        ((uint4*)(xp + ((size_t)h * WP) * C_IN))[c4] = z;
    } else if (i < 28800) {                            // w = 225 col, h 1..224
        int j = i - 21632; int h = 1 + (j >> 5); int c4 = j & 31;
        ((uint4*)(xp + ((size_t)h * WP + 225) * C_IN))[c4] = z;
    }
}

// x [C][H][W] f32 -> xp [HP][WP][C] bf16 (interior only)
__global__ void prep_x(const float* __restrict__ x, unsigned short* __restrict__ xp) {
    int b  = blockIdx.x;
    int ct = b & 3, wt = (b >> 2) & 3, h = b >> 4;   // grid = 224*4*4
    int c0 = ct * 64, w0 = wt * 64;
    int t  = threadIdx.x;
    __shared__ float tile[64][65];

    int w   = t & 63;
    int cl0 = t >> 6;      // 0..3
    #pragma unroll
    for (int i = 0; i < 16; ++i) {
        int cl = i * 4 + cl0;
        float v = 0.f;
        if (w0 + w < W_IN)
            v = x[(size_t)(c0 + cl) * NPIX + (size_t)h * W_IN + w0 + w];
        tile[cl][w] = v;
    }
    __syncthreads();

    int wc = t >> 2;           // 0..63
    int cc = (t & 3) * 16;     // 0,16,32,48
    if (w0 + wc < W_IN) {
        uint32_t pk[8];
        #pragma unroll
        for (int j = 0; j < 8; ++j) {
            unsigned short lo = f2bf(tile[cc + 2 * j][wc]);
            unsigned short hi = f2bf(tile[cc + 2 * j + 1][wc]);
            pk[j] = (uint32_t)lo | ((uint32_t)hi << 16);
        }
        size_t base = ((size_t)(h + 1) * WP + (w0 + wc + 1)) * C_IN + c0 + cc;
        uint4* dst = (uint4*)(xp + base);
        dst[0] = make_uint4(pk[0], pk[1], pk[2], pk[3]);
        dst[1] = make_uint4(pk[4], pk[5], pk[6], pk[7]);
    }
}

// ---------- main GEMM: out[o][n] = sum_p sum_c wb[p][o][c] * xp[...][c] ----------
// A (weights) lives in REGISTERS, loaded global->reg each K-step (L1/L2-hot,
// wave-pairs share identical addresses). Only B (pixels) is LDS-staged:
// 2 bufs x 16 KB = 32 KB -> 3 blocks/CU (quantization 784/768 ~ 1.02 rounds).
// Counted-vmcnt body(t):  LOAD_A(t)[8] ; STAGE_B(t+1)[4] ; vmcnt(4)
//   [drains B(t)+A(t), keeps B(t+1) in flight] ; barrier ; 8x ds_read_b128 ;
//   lgkm(0) ; 32 MFMA ; barrier.
// B swizzle (verified 0-conflict): phys_quad = logical_quad ^ (row&7).

__launch_bounds__(256, 3)
__global__ void conv_gemm(const unsigned short* __restrict__ xp,
                          const unsigned short* __restrict__ wb,
                          float* __restrict__ out) {
    // bijective XCD swizzle: 784 % 8 == 0, chunk = 98 per XCD
    int wgid = (blockIdx.x & 7) * 98 + (blockIdx.x >> 3);
    int mt = wgid & 1;
    int nt = wgid >> 1;
    int m0 = mt * BM;
    int n0 = nt * BN;
    int t  = threadIdx.x;
    int l  = t & 63, wv = t >> 6;

    __shared__ __align__(16) unsigned short lds[2 * 8192];   // 32 KB (B only)

    // ---- B staging: 16 chunks of 8 rows (1 KB); wave wv owns chunks 4wv..4wv+3.
    // lane l -> row_in_chunk = l>>3, phys quad = l&7,
    // logical quad = (l&7) ^ (row&7) = (l&7) ^ (l>>3).
    int q8 = ((l & 7) ^ (l >> 3)) * 8;
    int rA = l >> 3;
    int offB0, offB1, offB2, offB3;
    {
        int r0 = (wv * 4 + 0) * 8 + rA;
        int r1 = (wv * 4 + 1) * 8 + rA;
        int r2 = (wv * 4 + 2) * 8 + rA;
        int r3 = (wv * 4 + 3) * 8 + rA;
        int nc0 = n0 + r0, nc1 = n0 + r1, nc2 = n0 + r2, nc3 = n0 + r3;
        int h0 = nc0 / W_IN, h1 = nc1 / W_IN, h2 = nc2 / W_IN, h3 = nc3 / W_IN;
        offB0 = (h0 * WP + (nc0 - h0 * W_IN)) * C_IN + q8;
        offB1 = (h1 * WP + (nc1 - h1 * W_IN)) * C_IN + q8;
        offB2 = (h2 * WP + (nc2 - h2 * W_IN)) * C_IN + q8;
        offB3 = (h3 * WP + (nc3 - h3 * W_IN)) * C_IN + q8;
    }

    // ---- fragment addressing ----
    int la = l & 15;
    int lk = l >> 4;                    // k sub-quad 0..3
    int mo = (wv >> 1) * 64;
    int no = (wv & 1) * 64;
    int xq0 = ((0 * 4 + lk) ^ (la & 7)) * 8;   // B read swizzle, k-half 0
    int xq1 = ((1 * 4 + lk) ^ (la & 7)) * 8;   // B read swizzle, k-half 1
    int aRow = (m0 + mo + la) * C_IN + lk * 8; // A reg-load base (no swizzle)

    f32x4 acc[4][4];
    #pragma unroll
    for (int i = 0; i < 4; ++i)
        #pragma unroll
        for (int j = 0; j < 4; ++j)
            acc[i][j] = f32x4{0.f, 0.f, 0.f, 0.f};

    short8 aR[4][2];   // A fragments for current step (static indexing only)

#define STAGE_B(BD, S) do {                                                  \
    int s_ = (S);                                                            \
    int p_ = s_ >> 2, cs_ = (s_ & 3) << 6;                                   \
    int kh_ = (p_ * 11) >> 5; int kw_ = p_ - 3 * kh_;                        \
    const unsigned short* bS_ = xp + (kh_ * WP + kw_) * C_IN + cs_;          \
    gl_lds16(bS_ + offB0, &lds[(BD) * 8192 + (wv * 4 + 0) * 512]);           \
    gl_lds16(bS_ + offB1, &lds[(BD) * 8192 + (wv * 4 + 1) * 512]);           \
    gl_lds16(bS_ + offB2, &lds[(BD) * 8192 + (wv * 4 + 2) * 512]);           \
    gl_lds16(bS_ + offB3, &lds[(BD) * 8192 + (wv * 4 + 3) * 512]);           \
} while (0)

#define LOAD_A(S) do {                                                       \
    int s_ = (S);                                                            \
    const unsigned short* aS_ = wb + (s_ >> 2) * 65536 + ((s_ & 3) << 6) + aRow; \
    _Pragma("unroll")                                                        \
    for (int i_ = 0; i_ < 4; ++i_) {                                         \
        aR[i_][0] = *(const short8*)(aS_ + i_ * 16 * C_IN);                  \
        aR[i_][1] = *(const short8*)(aS_ + i_ * 16 * C_IN + 32);             \
    }                                                                        \
} while (0)

#define BODY(BC, S, DO_STAGE) do {                                           \
    LOAD_A(S);                                                               \
    if (DO_STAGE) STAGE_B((BC) ^ 1, (S) + 1);                                \
    asm volatile("s_waitcnt vmcnt(%0)" :: "i"((DO_STAGE) ? 4 : 0) : "memory"); \
    __builtin_amdgcn_sched_barrier(0);                                       \
    __builtin_amdgcn_s_barrier();                                            \
    __builtin_amdgcn_sched_barrier(0);                                       \
    short8 b0_[4], b1_[4];                                                   \
    _Pragma("unroll")                                                        \
    for (int i_ = 0; i_ < 4; ++i_) {                                         \
        b0_[i_] = *(const short8*)&lds[(BC) * 8192 + (no + i_ * 16 + la) * BK + xq0]; \
        b1_[i_] = *(const short8*)&lds[(BC) * 8192 + (no + i_ * 16 + la) * BK + xq1]; \
    }                                                                        \
    asm volatile("s_waitcnt lgkmcnt(0)" ::: "memory");                       \
    __builtin_amdgcn_sched_barrier(0);                                       \
    __builtin_amdgcn_s_setprio(1);                                           \
    _Pragma("unroll")                                                        \
    for (int i_ = 0; i_ < 4; ++i_)                                           \
        _Pragma("unroll")                                                    \
        for (int j_ = 0; j_ < 4; ++j_)                                       \
            acc[i_][j_] = __builtin_amdgcn_mfma_f32_16x16x32_bf16(           \
                aR[i_][0], b0_[j_], acc[i_][j_], 0, 0, 0);                   \
    _Pragma("unroll")                                                        \
    for (int i_ = 0; i_ < 4; ++i_)                                           \
        _Pragma("unroll")                                                    \
        for (int j_ = 0; j_ < 4; ++j_)                                       \
            acc[i_][j_] = __builtin_amdgcn_mfma_f32_16x16x32_bf16(           \
                aR[i_][1], b1_[j_], acc[i_][j_], 0, 0, 0);                   \
    __builtin_amdgcn_s_setprio(0);                                           \
    __builtin_amdgcn_sched_barrier(0);                                       \
    __builtin_amdgcn_s_barrier();                                            \
    __builtin_amdgcn_sched_barrier(0);                                       \
} while (0)

    // 36 K-steps total (9 taps x 4 c-slices of 64)
    STAGE_B(0, 0);
    #pragma unroll 1
    for (int k = 0; k < 17; ++k) {      // s = 0..33
        BODY(0, 2 * k, 1);
        BODY(1, 2 * k + 1, 1);
    }
    BODY(0, 34, 1);                     // stages s=35 into buf1
    BODY(1, 35, 0);                     // final, drains all

#undef BODY
#undef LOAD_A
#undef STAGE_B

    // epilogue: D frag col = l&15 (n), row = (l>>4)*4 + r (o)
    int ro = lk * 4;
    #pragma unroll
    for (int i = 0; i < 4; ++i) {
        #pragma unroll
        for (int j = 0; j < 4; ++j) {
            int oo = m0 + mo + i * 16 + ro;
            int nn = n0 + no + j * 16 + la;
            #pragma unroll
            for (int r = 0; r < 4; ++r)
                out[(size_t)(oo + r) * NPIX + nn] = acc[i][j][r];
        }
    }
}

// ---------- fallback (tiny ws): naive direct conv, correct but slow ----------
__global__ void conv_naive(const float* __restrict__ x, const float* __restrict__ wk,
                           float* __restrict__ out) {
    int idx = blockIdx.x * 256 + threadIdx.x;   // o*NPIX + n
    int n = idx % NPIX;
    int o = idx / NPIX;
    int h = n / W_IN, w = n - (n / W_IN) * W_IN;
    float s = 0.f;
    for (int c = 0; c < C_IN; ++c) {
        const float* xc = x + (size_t)c * NPIX;
        const float* wc = wk + ((size_t)o * C_IN + c) * 9;
        #pragma unroll
        for (int kh = 0; kh < 3; ++kh) {
            int hh = h + kh - 1;
            if (hh < 0 || hh >= H_IN) continue;
            #pragma unroll
            for (int kw = 0; kw < 3; ++kw) {
                int ww = w + kw - 1;
                if (ww < 0 || ww >= W_IN) continue;
                s += xc[hh * W_IN + ww] * wc[kh * 3 + kw];
            }
        }
    }
    out[idx] = s;
}

extern "C" void kernel_launch(void* const* d_in, const int* in_sizes, int n_in,
                              void* d_out, int out_size, void* d_ws, size_t ws_size,
                              hipStream_t stream) {
    const float* x  = (const float*)d_in[0];
    const float* wk = (const float*)d_in[1];
    float* out = (float*)d_out;

    const size_t xp_elems = (size_t)HP * WP * C_IN;   // 13,075,456
    const size_t wb_elems = (size_t)9 * 256 * 256;    // 589,824
    const size_t need = (xp_elems + wb_elems) * 2;    // ~27.3 MB

    if (ws_size < need) {
        conv_naive<<<(C_OUT * NPIX) / 256, 256, 0, stream>>>(x, wk, out);
        return;
    }

    unsigned short* xp = (unsigned short*)d_ws;
    unsigned short* wb = xp + xp_elems;

    prep_misc<<<2304 + 113, 256, 0, stream>>>(wk, wb, xp);
    prep_x<<<224 * 16, 256, 0, stream>>>(x, xp);
    conv_gemm<<<392 * 2, 256, 0, stream>>>(xp, wb, out);
}

// Round 8
// 89.702 us; speedup vs baseline: 2.0467x; 2.0467x over previous
//
#include <hip/hip_runtime.h>
#include <hip/hip_bf16.h>
#include <stdint.h>

#define C_IN  256
#define C_OUT 256
#define H_IN  224
#define W_IN  224
#define HP    226
#define WP    226
#define NPIX  (H_IN * W_IN)   // 50176 = 392 * 128
#define BM    128
#define BN    128
#define BK    64              // 128 B rows -> XOR-(row&7) swizzle, 0 conflicts (r2/r5 empirics)

typedef __attribute__((ext_vector_type(8))) short short8;
typedef __attribute__((ext_vector_type(4))) float f32x4;

__device__ __forceinline__ unsigned short f2bf(float f) {
    __hip_bfloat16 b = __float2bfloat16(f);
    return *(unsigned short*)&b;
}

// async global->LDS, 16B per lane; LDS dest is wave-uniform base + lane*16
__device__ __forceinline__ void gl_lds16(const unsigned short* g, unsigned short* l) {
    __builtin_amdgcn_global_load_lds(
        (const __attribute__((address_space(1))) unsigned int*)g,
        (__attribute__((address_space(3))) unsigned int*)l,
        16, 0, 0);
}

// ---------- merged prep kernel ----------
// blocks [0,3584): x [C][H][W] f32 -> xp [HP][WP][C] bf16 (interior)
// blocks [3584,5888): W [O][C][3][3] f32 -> wb [p][O][C] bf16
// blocks [5888,6001): zero xp pad border
__global__ void prep_all(const float* __restrict__ x, const float* __restrict__ wk,
                         unsigned short* __restrict__ xp, unsigned short* __restrict__ wb) {
    int b = blockIdx.x;
    int t = threadIdx.x;
    if (b < 3584) {
        int ct = b & 3, wt = (b >> 2) & 3, h = b >> 4;   // 224*4*4
        int c0 = ct * 64, w0 = wt * 64;
        __shared__ float tile[64][65];
        int w   = t & 63;
        int cl0 = t >> 6;
        #pragma unroll
        for (int i = 0; i < 16; ++i) {
            int cl = i * 4 + cl0;
            float v = 0.f;
            if (w0 + w < W_IN)
                v = x[(size_t)(c0 + cl) * NPIX + (size_t)h * W_IN + w0 + w];
            tile[cl][w] = v;
        }
        __syncthreads();
        int wc = t >> 2;
        int cc = (t & 3) * 16;
        if (w0 + wc < W_IN) {
            uint32_t pk[8];
            #pragma unroll
            for (int j = 0; j < 8; ++j) {
                unsigned short lo = f2bf(tile[cc + 2 * j][wc]);
                unsigned short hi = f2bf(tile[cc + 2 * j + 1][wc]);
                pk[j] = (uint32_t)lo | ((uint32_t)hi << 16);
            }
            size_t base = ((size_t)(h + 1) * WP + (w0 + wc + 1)) * C_IN + c0 + cc;
            uint4* dst = (uint4*)(xp + base);
            dst[0] = make_uint4(pk[0], pk[1], pk[2], pk[3]);
            dst[1] = make_uint4(pk[4], pk[5], pk[6], pk[7]);
        }
        return;
    }
    if (b < 5888) {
        int idx = (b - 3584) * 256 + t;               // 9*256*256
        int c = idx & 255, o = (idx >> 8) & 255, p = idx >> 16;
        wb[((size_t)p * 256 + o) * 256 + c] = f2bf(wk[((size_t)o * 256 + c) * 9 + p]);
        return;
    }
    int i = (b - 5888) * 256 + t;                     // uint4 index
    uint4 z = make_uint4(0u, 0u, 0u, 0u);
    if (i < 7232) {
        ((uint4*)xp)[i] = z;
    } else if (i < 14464) {
        ((uint4*)(xp + (size_t)225 * WP * C_IN))[i - 7232] = z;
    } else if (i < 21632) {
        int j = i - 14464; int h = 1 + (j >> 5); int c4 = j & 31;
        ((uint4*)(xp + ((size_t)h * WP) * C_IN))[c4] = z;
    } else if (i < 28800) {
        int j = i - 21632; int h = 1 + (j >> 5); int c4 = j & 31;
        ((uint4*)(xp + ((size_t)h * WP + 225) * C_IN))[c4] = z;
    }
}

// ---------- main GEMM: out[o][n] = sum_p sum_c wb[p][o][c] * xp[...][c] ----------
// 48 KB LDS (A single-buf 16 KB + B dbuf 2x16 KB) -> 3 blocks/CU.
// body(t): vmcnt(0)+lgkm(0); barrier; STAGE_B(t+1 -> buf^1); read A frags;
//          lgkm(0); barrier; STAGE_A(t+1); read B frags + 32 MFMA (setprio).
// All DMA waited one full phase after issue; every LDS overwrite fenced by
// lgkm(0)+barrier. Swizzle (verified 0-conflict): phys_quad = logical ^ (row&7).

__launch_bounds__(256, 3)
__global__ void conv_gemm(const unsigned short* __restrict__ xp,
                          const unsigned short* __restrict__ wb,
                          float* __restrict__ out) {
    // bijective XCD swizzle: 784 % 8 == 0, chunk = 98 per XCD
    int wgid = (blockIdx.x & 7) * 98 + (blockIdx.x >> 3);
    int mt = wgid & 1;
    int nt = wgid >> 1;
    int m0 = mt * BM;
    int n0 = nt * BN;
    int t  = threadIdx.x;
    int l  = t & 63, wv = t >> 6;   // 4 waves

    // A: [0,8192) elems; B buf0: [8192,16384); B buf1: [16384,24576)
    __shared__ __align__(16) unsigned short lds[24576];   // 48 KB

    // staging: 16 chunks of 8 rows (1 KB) per matrix; wave wv owns chunks
    // 4wv..4wv+3. lane l -> row_in_chunk = l>>3, phys quad = l&7,
    // logical quad = (l&7) ^ (row&7) = (l&7) ^ (l>>3)
    int q8 = ((l & 7) ^ (l >> 3)) * 8;
    int rA = l >> 3;
    int offA0, offA1, offA2, offA3, offB0, offB1, offB2, offB3;
    {
        int r0 = (wv * 4 + 0) * 8 + rA;
        int r1 = (wv * 4 + 1) * 8 + rA;
        int r2 = (wv * 4 + 2) * 8 + rA;
        int r3 = (wv * 4 + 3) * 8 + rA;
        offA0 = (m0 + r0) * C_IN + q8;
        offA1 = (m0 + r1) * C_IN + q8;
        offA2 = (m0 + r2) * C_IN + q8;
        offA3 = (m0 + r3) * C_IN + q8;
        int nc0 = n0 + r0, nc1 = n0 + r1, nc2 = n0 + r2, nc3 = n0 + r3;
        int h0 = nc0 / W_IN, h1 = nc1 / W_IN, h2 = nc2 / W_IN, h3 = nc3 / W_IN;
        offB0 = (h0 * WP + (nc0 - h0 * W_IN)) * C_IN + q8;
        offB1 = (h1 * WP + (nc1 - h1 * W_IN)) * C_IN + q8;
        offB2 = (h2 * WP + (nc2 - h2 * W_IN)) * C_IN + q8;
        offB3 = (h3 * WP + (nc3 - h3 * W_IN)) * C_IN + q8;
    }

    // read-side fragment addressing
    int la = l & 15;
    int lk = l >> 4;                    // k sub-quad 0..3
    int mo = (wv >> 1) * 64;
    int no = (wv & 1) * 64;
    int xq0 = ((0 * 4 + lk) ^ (la & 7)) * 8;
    int xq1 = ((1 * 4 + lk) ^ (la & 7)) * 8;

    f32x4 acc[4][4];
    #pragma unroll
    for (int i = 0; i < 4; ++i)
        #pragma unroll
        for (int j = 0; j < 4; ++j)
            acc[i][j] = f32x4{0.f, 0.f, 0.f, 0.f};

#define TAPOFF(S, PV, CSV) int PV = (S) >> 2; int CSV = ((S) & 3) << 6;

#define STAGE_B(BC, S) do {                                                  \
    TAPOFF(S, p_, cs_)                                                       \
    int kh_ = (p_ * 11) >> 5; int kw_ = p_ - 3 * kh_;                        \
    const unsigned short* bS_ = xp + (kh_ * WP + kw_) * C_IN + cs_;          \
    gl_lds16(bS_ + offB0, &lds[8192 + (BC) * 8192 + (wv * 4 + 0) * 512]);    \
    gl_lds16(bS_ + offB1, &lds[8192 + (BC) * 8192 + (wv * 4 + 1) * 512]);    \
    gl_lds16(bS_ + offB2, &lds[8192 + (BC) * 8192 + (wv * 4 + 2) * 512]);    \
    gl_lds16(bS_ + offB3, &lds[8192 + (BC) * 8192 + (wv * 4 + 3) * 512]);    \
} while (0)

#define STAGE_A(S) do {                                                      \
    TAPOFF(S, p_, cs_)                                                       \
    const unsigned short* aS_ = wb + p_ * 65536 + cs_;                       \
    gl_lds16(aS_ + offA0, &lds[(wv * 4 + 0) * 512]);                         \
    gl_lds16(aS_ + offA1, &lds[(wv * 4 + 1) * 512]);                         \
    gl_lds16(aS_ + offA2, &lds[(wv * 4 + 2) * 512]);                         \
    gl_lds16(aS_ + offA3, &lds[(wv * 4 + 3) * 512]);                         \
} while (0)

#define BODY(BC, S, DO_STAGE) do {                                           \
    asm volatile("s_waitcnt vmcnt(0) lgkmcnt(0)" ::: "memory");              \
    __builtin_amdgcn_sched_barrier(0);                                       \
    __builtin_amdgcn_s_barrier();                                            \
    __builtin_amdgcn_sched_barrier(0);                                       \
    if (DO_STAGE) STAGE_B((BC) ^ 1, (S) + 1);                                \
    short8 af_[4][2];                                                        \
    _Pragma("unroll")                                                        \
    for (int i_ = 0; i_ < 4; ++i_) {                                         \
        af_[i_][0] = *(const short8*)&lds[(mo + i_ * 16 + la) * BK + xq0];   \
        af_[i_][1] = *(const short8*)&lds[(mo + i_ * 16 + la) * BK + xq1];   \
    }                                                                        \
    asm volatile("s_waitcnt lgkmcnt(0)" ::: "memory");                       \
    __builtin_amdgcn_sched_barrier(0);                                       \
    __builtin_amdgcn_s_barrier();                                            \
    __builtin_amdgcn_sched_barrier(0);                                       \
    if (DO_STAGE) STAGE_A((S) + 1);                                          \
    short8 b0_[4], b1_[4];                                                   \
    _Pragma("unroll")                                                        \
    for (int i_ = 0; i_ < 4; ++i_) {                                         \
        b0_[i_] = *(const short8*)&lds[8192 + (BC) * 8192 + (no + i_ * 16 + la) * BK + xq0]; \
        b1_[i_] = *(const short8*)&lds[8192 + (BC) * 8192 + (no + i_ * 16 + la) * BK + xq1]; \
    }                                                                        \
    __builtin_amdgcn_s_setprio(1);                                           \
    _Pragma("unroll")                                                        \
    for (int i_ = 0; i_ < 4; ++i_)                                           \
        _Pragma("unroll")                                                    \
        for (int j_ = 0; j_ < 4; ++j_)                                       \
            acc[i_][j_] = __builtin_amdgcn_mfma_f32_16x16x32_bf16(           \
                af_[i_][0], b0_[j_], acc[i_][j_], 0, 0, 0);                  \
    _Pragma("unroll")                                                        \
    for (int i_ = 0; i_ < 4; ++i_)                                           \
        _Pragma("unroll")                                                    \
        for (int j_ = 0; j_ < 4; ++j_)                                       \
            acc[i_][j_] = __builtin_amdgcn_mfma_f32_16x16x32_bf16(           \
                af_[i_][1], b1_[j_], acc[i_][j_], 0, 0, 0);                  \
    __builtin_amdgcn_s_setprio(0);                                           \
} while (0)

    // 36 K-steps total (9 taps x 4 c-slices of 64)
    STAGE_B(0, 0);
    STAGE_A(0);
    #pragma unroll 1
    for (int k = 0; k < 17; ++k) {      // s = 0..33
        BODY(0, 2 * k, 1);
        BODY(1, 2 * k + 1, 1);
    }
    BODY(0, 34, 1);                     // stages s=35 (B->buf1, A)
    BODY(1, 35, 0);                     // final

#undef BODY
#undef STAGE_A
#undef STAGE_B
#undef TAPOFF

    // epilogue: D frag col = l&15 (n), row = (l>>4)*4 + r (o)
    int ro = lk * 4;
    #pragma unroll
    for (int i = 0; i < 4; ++i) {
        #pragma unroll
        for (int j = 0; j < 4; ++j) {
            int oo = m0 + mo + i * 16 + ro;
            int nn = n0 + no + j * 16 + la;
            #pragma unroll
            for (int r = 0; r < 4; ++r)
                out[(size_t)(oo + r) * NPIX + nn] = acc[i][j][r];
        }
    }
}

// ---------- fallback (tiny ws): naive direct conv, correct but slow ----------
__global__ void conv_naive(const float* __restrict__ x, const float* __restrict__ wk,
                           float* __restrict__ out) {
    int idx = blockIdx.x * 256 + threadIdx.x;   // o*NPIX + n
    int n = idx % NPIX;
    int o = idx / NPIX;
    int h = n / W_IN, w = n - (n / W_IN) * W_IN;
    float s = 0.f;
    for (int c = 0; c < C_IN; ++c) {
        const float* xc = x + (size_t)c * NPIX;
        const float* wc = wk + ((size_t)o * C_IN + c) * 9;
        #pragma unroll
        for (int kh = 0; kh < 3; ++kh) {
            int hh = h + kh - 1;
            if (hh < 0 || hh >= H_IN) continue;
            #pragma unroll
            for (int kw = 0; kw < 3; ++kw) {
                int ww = w + kw - 1;
                if (ww < 0 || ww >= W_IN) continue;
                s += xc[hh * W_IN + ww] * wc[kh * 3 + kw];
            }
        }
    }
    out[idx] = s;
}

extern "C" void kernel_launch(void* const* d_in, const int* in_sizes, int n_in,
                              void* d_out, int out_size, void* d_ws, size_t ws_size,
                              hipStream_t stream) {
    const float* x  = (const float*)d_in[0];
    const float* wk = (const float*)d_in[1];
    float* out = (float*)d_out;

    const size_t xp_elems = (size_t)HP * WP * C_IN;   // 13,075,456
    const size_t wb_elems = (size_t)9 * 256 * 256;    // 589,824
    const size_t need = (xp_elems + wb_elems) * 2;    // ~27.3 MB

    if (ws_size < need) {
        conv_naive<<<(C_OUT * NPIX) / 256, 256, 0, stream>>>(x, wk, out);
        return;
    }

    unsigned short* xp = (unsigned short*)d_ws;
    unsigned short* wb = xp + xp_elems;

    prep_all<<<3584 + 2304 + 113, 256, 0, stream>>>(x, wk, xp, wb);
    conv_gemm<<<392 * 2, 256, 0, stream>>>(xp, wb, out);
}

// Round 9
// 88.821 us; speedup vs baseline: 2.0670x; 1.0099x over previous
//
#include <hip/hip_runtime.h>
#include <hip/hip_bf16.h>
#include <stdint.h>

#define C_IN  256
#define C_OUT 256
#define H_IN  224
#define W_IN  224
#define HP    226
#define WP    226
#define NPIX  (H_IN * W_IN)   // 50176 = 196 * 256
#define BM    256             // = full M -> every block reuses the same A panel (L2)
#define BN    256
#define BK    64              // 128 B rows -> XOR-(row&7) swizzle, 0 conflicts (r2/r5 empirics)

typedef __attribute__((ext_vector_type(8))) short short8;
typedef __attribute__((ext_vector_type(4))) float f32x4;

__device__ __forceinline__ unsigned short f2bf(float f) {
    __hip_bfloat16 b = __float2bfloat16(f);
    return *(unsigned short*)&b;
}

// async global->LDS, 16B per lane; LDS dest is wave-uniform base + lane*16
__device__ __forceinline__ void gl_lds16(const unsigned short* g, unsigned short* l) {
    __builtin_amdgcn_global_load_lds(
        (const __attribute__((address_space(1))) unsigned int*)g,
        (__attribute__((address_space(3))) unsigned int*)l,
        16, 0, 0);
}

// ---------- merged prep kernel ----------
// blocks [0,3584): x [C][H][W] f32 -> xp [HP][WP][C] bf16 (interior)
// blocks [3584,5888): W [O][C][3][3] f32 -> wb [p][O][C] bf16
// blocks [5888,6001): zero xp pad border
__global__ void prep_all(const float* __restrict__ x, const float* __restrict__ wk,
                         unsigned short* __restrict__ xp, unsigned short* __restrict__ wb) {
    int b = blockIdx.x;
    int t = threadIdx.x;
    if (b < 3584) {
        int ct = b & 3, wt = (b >> 2) & 3, h = b >> 4;   // 224*4*4
        int c0 = ct * 64, w0 = wt * 64;
        __shared__ float tile[64][65];
        int w   = t & 63;
        int cl0 = t >> 6;
        #pragma unroll
        for (int i = 0; i < 16; ++i) {
            int cl = i * 4 + cl0;
            float v = 0.f;
            if (w0 + w < W_IN)
                v = x[(size_t)(c0 + cl) * NPIX + (size_t)h * W_IN + w0 + w];
            tile[cl][w] = v;
        }
        __syncthreads();
        int wc = t >> 2;
        int cc = (t & 3) * 16;
        if (w0 + wc < W_IN) {
            uint32_t pk[8];
            #pragma unroll
            for (int j = 0; j < 8; ++j) {
                unsigned short lo = f2bf(tile[cc + 2 * j][wc]);
                unsigned short hi = f2bf(tile[cc + 2 * j + 1][wc]);
                pk[j] = (uint32_t)lo | ((uint32_t)hi << 16);
            }
            size_t base = ((size_t)(h + 1) * WP + (w0 + wc + 1)) * C_IN + c0 + cc;
            uint4* dst = (uint4*)(xp + base);
            dst[0] = make_uint4(pk[0], pk[1], pk[2], pk[3]);
            dst[1] = make_uint4(pk[4], pk[5], pk[6], pk[7]);
        }
        return;
    }
    if (b < 5888) {
        int idx = (b - 3584) * 256 + t;               // 9*256*256
        int c = idx & 255, o = (idx >> 8) & 255, p = idx >> 16;
        wb[((size_t)p * 256 + o) * 256 + c] = f2bf(wk[((size_t)o * 256 + c) * 9 + p]);
        return;
    }
    int i = (b - 5888) * 256 + t;                     // uint4 index
    uint4 z = make_uint4(0u, 0u, 0u, 0u);
    if (i < 7232) {
        ((uint4*)xp)[i] = z;
    } else if (i < 14464) {
        ((uint4*)(xp + (size_t)225 * WP * C_IN))[i - 7232] = z;
    } else if (i < 21632) {
        int j = i - 14464; int h = 1 + (j >> 5); int c4 = j & 31;
        ((uint4*)(xp + ((size_t)h * WP) * C_IN))[c4] = z;
    } else if (i < 28800) {
        int j = i - 21632; int h = 1 + (j >> 5); int c4 = j & 31;
        ((uint4*)(xp + ((size_t)h * WP + 225) * C_IN))[c4] = z;
    }
}

// ---------- main GEMM: out[o][n] = sum_p sum_c wb[p][o][c] * xp[...][c] ----------
// 256x256 tile, 8 waves (2M x 4N), wave tile 128x64 (M_rep=8, N_rep=4):
// fragment-read bytes/MFMA 0.375 KB (vs 0.5 at 64x64), DMA-write bytes/MFMA
// 0.125 KB (vs 0.25 at 128^2). Schedule = r5's proven counted-vmcnt body:
//   STAGE(t+1 -> buf^1)[8/wave] ; vmcnt(8) [t complete, t+1 in flight across
//   barriers + full compute] ; barrier ; 24 swizzled ds_read_b128 ; lgkm0 ;
//   64 MFMA (2 k-half groups, setprio) ; lgkm0 ; barrier.
// Swizzle (verified 0-conflict): phys_quad = logical_quad ^ (row&7), write
// side via pre-swizzled global source, read side via XOR'd ds_read offset.

__launch_bounds__(512, 2)
__global__ void conv_gemm(const unsigned short* __restrict__ xp,
                          const unsigned short* __restrict__ wb,
                          float* __restrict__ out) {
    int nt = blockIdx.x;           // 196 n-tiles; BM == M so no m-tiling
    int n0 = nt * BN;
    int t  = threadIdx.x;
    int l  = t & 63, wv = t >> 6;  // 8 waves

    // per buf: A [256][64] at 0..16384 elems, B [256][64] at 16384..32768
    __shared__ __align__(16) unsigned short lds[2 * 32768];   // 128 KB

    // ---- staging: 32 chunks of 8 rows (1 KB) per matrix; wave wv owns
    // chunks 4wv..4wv+3 of A and of B. lane l -> row_in_chunk = l>>3,
    // phys quad = l&7, logical quad = (l&7) ^ (row&7) = (l&7) ^ (l>>3).
    int q8 = ((l & 7) ^ (l >> 3)) * 8;
    int rA = l >> 3;
    int offA0, offA1, offA2, offA3, offB0, offB1, offB2, offB3;
    {
        int r0 = (wv * 4 + 0) * 8 + rA;    // 0..255
        int r1 = (wv * 4 + 1) * 8 + rA;
        int r2 = (wv * 4 + 2) * 8 + rA;
        int r3 = (wv * 4 + 3) * 8 + rA;
        offA0 = r0 * C_IN + q8;
        offA1 = r1 * C_IN + q8;
        offA2 = r2 * C_IN + q8;
        offA3 = r3 * C_IN + q8;
        int nc0 = n0 + r0, nc1 = n0 + r1, nc2 = n0 + r2, nc3 = n0 + r3;
        int h0 = nc0 / W_IN, h1 = nc1 / W_IN, h2 = nc2 / W_IN, h3 = nc3 / W_IN;
        offB0 = (h0 * WP + (nc0 - h0 * W_IN)) * C_IN + q8;
        offB1 = (h1 * WP + (nc1 - h1 * W_IN)) * C_IN + q8;
        offB2 = (h2 * WP + (nc2 - h2 * W_IN)) * C_IN + q8;
        offB3 = (h3 * WP + (nc3 - h3 * W_IN)) * C_IN + q8;
    }

    // ---- read-side fragment addressing ----
    int la = l & 15;
    int lk = l >> 4;                    // k sub-quad 0..3
    int wr = wv >> 2;                   // 0..1 -> m-half
    int wc = wv & 3;                    // 0..3 -> n-quarter
    int mo = wr * 128;
    int no = wc * 64;
    int xq0 = ((0 * 4 + lk) ^ (la & 7)) * 8;
    int xq1 = ((1 * 4 + lk) ^ (la & 7)) * 8;

    f32x4 acc[8][4];
    #pragma unroll
    for (int i = 0; i < 8; ++i)
        #pragma unroll
        for (int j = 0; j < 4; ++j)
            acc[i][j] = f32x4{0.f, 0.f, 0.f, 0.f};

#define STAGE(BD, S) do {                                                    \
    int s_ = (S);                                                            \
    int p_ = s_ >> 2, cs_ = (s_ & 3) << 6;                                   \
    int kh_ = (p_ * 11) >> 5; int kw_ = p_ - 3 * kh_;                        \
    const unsigned short* aS_ = wb + p_ * 65536 + cs_;                       \
    const unsigned short* bS_ = xp + (kh_ * WP + kw_) * C_IN + cs_;          \
    gl_lds16(aS_ + offA0, &lds[(BD) * 32768 + (wv * 4 + 0) * 512]);          \
    gl_lds16(aS_ + offA1, &lds[(BD) * 32768 + (wv * 4 + 1) * 512]);          \
    gl_lds16(aS_ + offA2, &lds[(BD) * 32768 + (wv * 4 + 2) * 512]);          \
    gl_lds16(aS_ + offA3, &lds[(BD) * 32768 + (wv * 4 + 3) * 512]);          \
    gl_lds16(bS_ + offB0, &lds[(BD) * 32768 + 16384 + (wv * 4 + 0) * 512]);  \
    gl_lds16(bS_ + offB1, &lds[(BD) * 32768 + 16384 + (wv * 4 + 1) * 512]);  \
    gl_lds16(bS_ + offB2, &lds[(BD) * 32768 + 16384 + (wv * 4 + 2) * 512]);  \
    gl_lds16(bS_ + offB3, &lds[(BD) * 32768 + 16384 + (wv * 4 + 3) * 512]);  \
} while (0)

#define MFMA_HALF(BC, XQ) do {                                               \
    short8 af_[8], bf_[4];                                                   \
    _Pragma("unroll")                                                        \
    for (int i_ = 0; i_ < 8; ++i_)                                           \
        af_[i_] = *(const short8*)&lds[(BC) * 32768 + (mo + i_ * 16 + la) * BK + (XQ)]; \
    _Pragma("unroll")                                                        \
    for (int j_ = 0; j_ < 4; ++j_)                                           \
        bf_[j_] = *(const short8*)&lds[(BC) * 32768 + 16384 + (no + j_ * 16 + la) * BK + (XQ)]; \
    asm volatile("s_waitcnt lgkmcnt(0)" ::: "memory");                       \
    __builtin_amdgcn_sched_barrier(0);                                       \
    __builtin_amdgcn_s_setprio(1);                                           \
    _Pragma("unroll")                                                        \
    for (int i_ = 0; i_ < 8; ++i_)                                           \
        _Pragma("unroll")                                                    \
        for (int j_ = 0; j_ < 4; ++j_)                                       \
            acc[i_][j_] = __builtin_amdgcn_mfma_f32_16x16x32_bf16(           \
                af_[i_], bf_[j_], acc[i_][j_], 0, 0, 0);                     \
    __builtin_amdgcn_s_setprio(0);                                           \
} while (0)

#define BODY(BC, S, DO_STAGE) do {                                           \
    if (DO_STAGE) STAGE((BC) ^ 1, (S) + 1);                                  \
    asm volatile("s_waitcnt vmcnt(%0)" :: "i"((DO_STAGE) ? 8 : 0) : "memory"); \
    __builtin_amdgcn_sched_barrier(0);                                       \
    __builtin_amdgcn_s_barrier();                                            \
    __builtin_amdgcn_sched_barrier(0);                                       \
    MFMA_HALF(BC, xq0);                                                      \
    MFMA_HALF(BC, xq1);                                                      \
    asm volatile("s_waitcnt lgkmcnt(0)" ::: "memory");                       \
    __builtin_amdgcn_sched_barrier(0);                                       \
    __builtin_amdgcn_s_barrier();                                            \
    __builtin_amdgcn_sched_barrier(0);                                       \
} while (0)

    // 36 K-steps total (9 taps x 4 c-slices of 64)
    STAGE(0, 0);
    #pragma unroll 1
    for (int k = 0; k < 17; ++k) {      // s = 0..33
        BODY(0, 2 * k, 1);
        BODY(1, 2 * k + 1, 1);
    }
    BODY(0, 34, 1);                     // stages s=35 into buf1
    BODY(1, 35, 0);                     // final

#undef BODY
#undef MFMA_HALF
#undef STAGE

    // epilogue: D frag col = l&15 (n), row = (l>>4)*4 + r (o)
    int ro = lk * 4;
    #pragma unroll
    for (int i = 0; i < 8; ++i) {
        #pragma unroll
        for (int j = 0; j < 4; ++j) {
            int oo = mo + i * 16 + ro;
            int nn = n0 + no + j * 16 + la;
            #pragma unroll
            for (int r = 0; r < 4; ++r)
                out[(size_t)(oo + r) * NPIX + nn] = acc[i][j][r];
        }
    }
}

// ---------- fallback (tiny ws): naive direct conv, correct but slow ----------
__global__ void conv_naive(const float* __restrict__ x, const float* __restrict__ wk,
                           float* __restrict__ out) {
    int idx = blockIdx.x * 256 + threadIdx.x;   // o*NPIX + n
    int n = idx % NPIX;
    int o = idx / NPIX;
    int h = n / W_IN, w = n - (n / W_IN) * W_IN;
    float s = 0.f;
    for (int c = 0; c < C_IN; ++c) {
        const float* xc = x + (size_t)c * NPIX;
        const float* wc = wk + ((size_t)o * C_IN + c) * 9;
        #pragma unroll
        for (int kh = 0; kh < 3; ++kh) {
            int hh = h + kh - 1;
            if (hh < 0 || hh >= H_IN) continue;
            #pragma unroll
            for (int kw = 0; kw < 3; ++kw) {
                int ww = w + kw - 1;
                if (ww < 0 || ww >= W_IN) continue;
                s += xc[hh * W_IN + ww] * wc[kh * 3 + kw];
            }
        }
    }
    out[idx] = s;
}

extern "C" void kernel_launch(void* const* d_in, const int* in_sizes, int n_in,
                              void* d_out, int out_size, void* d_ws, size_t ws_size,
                              hipStream_t stream) {
    const float* x  = (const float*)d_in[0];
    const float* wk = (const float*)d_in[1];
    float* out = (float*)d_out;

    const size_t xp_elems = (size_t)HP * WP * C_IN;   // 13,075,456
    const size_t wb_elems = (size_t)9 * 256 * 256;    // 589,824
    const size_t need = (xp_elems + wb_elems) * 2;    // ~27.3 MB

    if (ws_size < need) {
        conv_naive<<<(C_OUT * NPIX) / 256, 256, 0, stream>>>(x, wk, out);
        return;
    }

    unsigned short* xp = (unsigned short*)d_ws;
    unsigned short* wb = xp + xp_elems;

    prep_all<<<3584 + 2304 + 113, 256, 0, stream>>>(x, wk, xp, wb);
    conv_gemm<<<196, 512, 0, stream>>>(xp, wb, out);
}

// Round 10
// 80.923 us; speedup vs baseline: 2.2687x; 1.0976x over previous
//
#include <hip/hip_runtime.h>
#include <hip/hip_bf16.h>
#include <stdint.h>

#define C_IN  256
#define C_OUT 256
#define H_IN  224
#define W_IN  224
#define HP    226
#define WP    226
#define NPIX  (H_IN * W_IN)   // 50176 = 196 * 256
#define BM    256             // = full M
#define BN    256
#define BK    64              // 128 B rows -> XOR-(row&7) swizzle, 0 conflicts (r2/r5/r9 empirics)

typedef __attribute__((ext_vector_type(8))) short short8;
typedef __attribute__((ext_vector_type(4))) float f32x4;

__device__ __forceinline__ unsigned short f2bf(float f) {
    __hip_bfloat16 b = __float2bfloat16(f);
    return *(unsigned short*)&b;
}

// async global->LDS, 16B per lane; LDS dest is wave-uniform base + lane*16
__device__ __forceinline__ void gl_lds16(const unsigned short* g, unsigned short* l) {
    __builtin_amdgcn_global_load_lds(
        (const __attribute__((address_space(1))) unsigned int*)g,
        (__attribute__((address_space(3))) unsigned int*)l,
        16, 0, 0);
}

// ---------- merged prep kernel ----------
__global__ void prep_all(const float* __restrict__ x, const float* __restrict__ wk,
                         unsigned short* __restrict__ xp, unsigned short* __restrict__ wb) {
    int b = blockIdx.x;
    int t = threadIdx.x;
    if (b < 3584) {
        int ct = b & 3, wt = (b >> 2) & 3, h = b >> 4;   // 224*4*4
        int c0 = ct * 64, w0 = wt * 64;
        __shared__ float tile[64][65];
        int w   = t & 63;
        int cl0 = t >> 6;
        #pragma unroll
        for (int i = 0; i < 16; ++i) {
            int cl = i * 4 + cl0;
            float v = 0.f;
            if (w0 + w < W_IN)
                v = x[(size_t)(c0 + cl) * NPIX + (size_t)h * W_IN + w0 + w];
            tile[cl][w] = v;
        }
        __syncthreads();
        int wc = t >> 2;
        int cc = (t & 3) * 16;
        if (w0 + wc < W_IN) {
            uint32_t pk[8];
            #pragma unroll
            for (int j = 0; j < 8; ++j) {
                unsigned short lo = f2bf(tile[cc + 2 * j][wc]);
                unsigned short hi = f2bf(tile[cc + 2 * j + 1][wc]);
                pk[j] = (uint32_t)lo | ((uint32_t)hi << 16);
            }
            size_t base = ((size_t)(h + 1) * WP + (w0 + wc + 1)) * C_IN + c0 + cc;
            uint4* dst = (uint4*)(xp + base);
            dst[0] = make_uint4(pk[0], pk[1], pk[2], pk[3]);
            dst[1] = make_uint4(pk[4], pk[5], pk[6], pk[7]);
        }
        return;
    }
    if (b < 5888) {
        int idx = (b - 3584) * 256 + t;               // 9*256*256
        int c = idx & 255, o = (idx >> 8) & 255, p = idx >> 16;
        wb[((size_t)p * 256 + o) * 256 + c] = f2bf(wk[((size_t)o * 256 + c) * 9 + p]);
        return;
    }
    int i = (b - 5888) * 256 + t;                     // uint4 index
    uint4 z = make_uint4(0u, 0u, 0u, 0u);
    if (i < 7232) {
        ((uint4*)xp)[i] = z;
    } else if (i < 14464) {
        ((uint4*)(xp + (size_t)225 * WP * C_IN))[i - 7232] = z;
    } else if (i < 21632) {
        int j = i - 14464; int h = 1 + (j >> 5); int c4 = j & 31;
        ((uint4*)(xp + ((size_t)h * WP) * C_IN))[c4] = z;
    } else if (i < 28800) {
        int j = i - 21632; int h = 1 + (j >> 5); int c4 = j & 31;
        ((uint4*)(xp + ((size_t)h * WP + 225) * C_IN))[c4] = z;
    }
}

// ---------- main GEMM ----------
// 256x256 tile, 8 waves (2M x 4N), wave tile 128x64, acc[8][4]. 128 KB LDS,
// 1 block/CU. Half-iteration = 1 K-tile (BK=64), 4 sub-phases:
//   ph1: STAGE quarter0 of tile t+1 -> buf c^1 ; vmcnt(2) [clears tile t's 8
//        loads, keeps the new 2 in flight] ; barrier ; bf(k0) + af(g0,k0)
//        reads ; 16 MFMA
//   ph2: STAGE q1 ; af(g1,k0) ; 16 MFMA
//   ph3: STAGE q2 ; bf(k1) + af(g0,k1) ; 16 MFMA
//   ph4: STAGE q3 ; af(g1,k1) ; 16 MFMA ; lgkm0 ; barrier
// Race-freedom: buf c^1 was fully read before the PREVIOUS closing
// lgkm0+barrier (so staging into it is legal); tile t's loads are ensured by
// every wave's vmcnt(2) before the opening barrier. Only 2 barriers per
// K-tile; stage-issues float among MFMA groups (compiler-scheduled).
// Swizzle (verified 0-conflict): phys_quad = logical_quad ^ (row&7).

__launch_bounds__(512, 2)
__global__ void conv_gemm(const unsigned short* __restrict__ xp,
                          const unsigned short* __restrict__ wb,
                          float* __restrict__ out) {
    // bijective chunked XCD swizzle, 196 blocks = 8*24 + 4 (m204 form)
    int bid = blockIdx.x;
    int xcd = bid & 7, orig = bid >> 3;
    int nt = (xcd < 4 ? xcd * 25 : 100 + (xcd - 4) * 24) + orig;
    int n0 = nt * BN;
    int t  = threadIdx.x;
    int l  = t & 63, wv = t >> 6;   // 8 waves

    // per buf (32768 elems): A [256][64] at +0, B [256][64] at +16384
    __shared__ __align__(16) unsigned short lds[2 * 32768];   // 128 KB

    // staging: each 16 KB quarter = 16 chunks of 1 KB; wave wv owns chunks
    // 2wv, 2wv+1. lane l -> row_in_chunk = l>>3, phys quad = l&7,
    // logical quad = (l&7) ^ (row&7) = (l&7) ^ (l>>3).
    int q8 = ((l & 7) ^ (l >> 3)) * 8;
    int rA = l >> 3;
    int rowLo = 16 * wv + rA;       // 0..127 within quarter
    int rowHi = rowLo + 8;
    int offA00 = rowLo * C_IN + q8;          // A quarter 0 (rows 0-127)
    int offA01 = rowHi * C_IN + q8;
    int offA10 = (128 + rowLo) * C_IN + q8;  // A quarter 1 (rows 128-255)
    int offA11 = (128 + rowHi) * C_IN + q8;
    int offB00, offB01, offB10, offB11;
    {
        int nc;
        nc = n0 + rowLo;       { int h_ = nc / W_IN; offB00 = (h_ * WP + nc - h_ * W_IN) * C_IN + q8; }
        nc = n0 + rowHi;       { int h_ = nc / W_IN; offB01 = (h_ * WP + nc - h_ * W_IN) * C_IN + q8; }
        nc = n0 + 128 + rowLo; { int h_ = nc / W_IN; offB10 = (h_ * WP + nc - h_ * W_IN) * C_IN + q8; }
        nc = n0 + 128 + rowHi; { int h_ = nc / W_IN; offB11 = (h_ * WP + nc - h_ * W_IN) * C_IN + q8; }
    }

    // read-side fragment addressing
    int la = l & 15;
    int lk = l >> 4;
    int wr = wv >> 2;                 // 0..1 -> m-half
    int wc = wv & 3;                  // 0..3 -> n-quarter
    int mo = wr * 128;
    int no = wc * 64;
    int xq0 = (lk ^ (la & 7)) * 8;
    int xq1 = ((4 + lk) ^ (la & 7)) * 8;

    f32x4 acc[8][4];
    #pragma unroll
    for (int i = 0; i < 8; ++i)
        #pragma unroll
        for (int j = 0; j < 4; ++j)
            acc[i][j] = f32x4{0.f, 0.f, 0.f, 0.f};

// stage quarter H (0,1: A halves; 2,3: B halves) of K-tile S into buffer BD
#define STAGEH(BD, S, H) do {                                                \
    int s_ = (S), p_ = s_ >> 2, cs_ = (s_ & 3) << 6;                         \
    if ((H) < 2) {                                                           \
        const unsigned short* g_ = wb + p_ * 65536 + cs_;                    \
        unsigned short* d_ = &lds[(BD) * 32768 + (H) * 8192 + wv * 1024];    \
        gl_lds16(g_ + ((H) ? offA10 : offA00), d_);                          \
        gl_lds16(g_ + ((H) ? offA11 : offA01), d_ + 512);                    \
    } else {                                                                 \
        int kh_ = (p_ * 11) >> 5, kw_ = p_ - 3 * kh_;                        \
        const unsigned short* g_ = xp + (kh_ * WP + kw_) * C_IN + cs_;       \
        unsigned short* d_ = &lds[(BD) * 32768 + 16384 + ((H) - 2) * 8192 + wv * 1024]; \
        gl_lds16(g_ + ((H) == 3 ? offB10 : offB00), d_);                     \
        gl_lds16(g_ + ((H) == 3 ? offB11 : offB01), d_ + 512);               \
    }                                                                        \
} while (0)

#define MFMAG(AF, BF, GOFF) do {                                             \
    __builtin_amdgcn_s_setprio(1);                                           \
    _Pragma("unroll")                                                        \
    for (int i_ = 0; i_ < 4; ++i_)                                           \
        _Pragma("unroll")                                                    \
        for (int j_ = 0; j_ < 4; ++j_)                                       \
            acc[(GOFF) + i_][j_] = __builtin_amdgcn_mfma_f32_16x16x32_bf16(  \
                AF[i_], BF[j_], acc[(GOFF) + i_][j_], 0, 0, 0);              \
    __builtin_amdgcn_s_setprio(0);                                           \
} while (0)

// one K-tile: compute buf BC, stage K-tile SS into buf BC^1 (if DO_STAGE)
#define HALF(BC, SS, DO_STAGE, VMSTR) do {                                   \
    if (DO_STAGE) STAGEH(1 ^ (BC), SS, 0);                                   \
    asm volatile("s_waitcnt " VMSTR ::: "memory");                           \
    __builtin_amdgcn_sched_barrier(0);                                       \
    __builtin_amdgcn_s_barrier();                                            \
    __builtin_amdgcn_sched_barrier(0);                                       \
    short8 bf0_[4], bf1_[4], a_[4];                                          \
    _Pragma("unroll")                                                        \
    for (int j_ = 0; j_ < 4; ++j_)                                           \
        bf0_[j_] = *(const short8*)&lds[(BC) * 32768 + 16384 + (no + j_ * 16 + la) * BK + xq0]; \
    _Pragma("unroll")                                                        \
    for (int i_ = 0; i_ < 4; ++i_)                                           \
        a_[i_] = *(const short8*)&lds[(BC) * 32768 + (mo + i_ * 16 + la) * BK + xq0]; \
    MFMAG(a_, bf0_, 0);                                                      \
    if (DO_STAGE) STAGEH(1 ^ (BC), SS, 1);                                   \
    _Pragma("unroll")                                                        \
    for (int i_ = 0; i_ < 4; ++i_)                                           \
        a_[i_] = *(const short8*)&lds[(BC) * 32768 + (mo + 64 + i_ * 16 + la) * BK + xq0]; \
    MFMAG(a_, bf0_, 4);                                                      \
    if (DO_STAGE) STAGEH(1 ^ (BC), SS, 2);                                   \
    _Pragma("unroll")                                                        \
    for (int j_ = 0; j_ < 4; ++j_)                                           \
        bf1_[j_] = *(const short8*)&lds[(BC) * 32768 + 16384 + (no + j_ * 16 + la) * BK + xq1]; \
    _Pragma("unroll")                                                        \
    for (int i_ = 0; i_ < 4; ++i_)                                           \
        a_[i_] = *(const short8*)&lds[(BC) * 32768 + (mo + i_ * 16 + la) * BK + xq1]; \
    MFMAG(a_, bf1_, 0);                                                      \
    if (DO_STAGE) STAGEH(1 ^ (BC), SS, 3);                                   \
    _Pragma("unroll")                                                        \
    for (int i_ = 0; i_ < 4; ++i_)                                           \
        a_[i_] = *(const short8*)&lds[(BC) * 32768 + (mo + 64 + i_ * 16 + la) * BK + xq1]; \
    MFMAG(a_, bf1_, 4);                                                      \
    asm volatile("s_waitcnt lgkmcnt(0)" ::: "memory");                       \
    __builtin_amdgcn_sched_barrier(0);                                       \
    __builtin_amdgcn_s_barrier();                                            \
    __builtin_amdgcn_sched_barrier(0);                                       \
} while (0)

    // 36 K-tiles (9 taps x 4 c-slices of 64). Prologue: tile 0 -> buf0.
    STAGEH(0, 0, 0); STAGEH(0, 0, 1); STAGEH(0, 0, 2); STAGEH(0, 0, 3);
    #pragma unroll 1
    for (int k = 0; k < 17; ++k) {            // tiles 0..33
        HALF(0, 2 * k + 1, 1, "vmcnt(2)");    // compute 2k,   stage 2k+1
        HALF(1, 2 * k + 2, 1, "vmcnt(2)");    // compute 2k+1, stage 2k+2
    }
    HALF(0, 35, 1, "vmcnt(2)");               // compute 34, stage 35
    HALF(1, 0, 0, "vmcnt(0)");                // compute 35, drain

#undef HALF
#undef MFMAG
#undef STAGEH

    // epilogue: D frag col = l&15 (n), row = (l>>4)*4 + r (o)
    int ro = lk * 4;
    #pragma unroll
    for (int i = 0; i < 8; ++i) {
        #pragma unroll
        for (int j = 0; j < 4; ++j) {
            int oo = mo + i * 16 + ro;
            int nn = n0 + no + j * 16 + la;
            #pragma unroll
            for (int r = 0; r < 4; ++r)
                out[(size_t)(oo + r) * NPIX + nn] = acc[i][j][r];
        }
    }
}

// ---------- fallback (tiny ws): naive direct conv, correct but slow ----------
__global__ void conv_naive(const float* __restrict__ x, const float* __restrict__ wk,
                           float* __restrict__ out) {
    int idx = blockIdx.x * 256 + threadIdx.x;   // o*NPIX + n
    int n = idx % NPIX;
    int o = idx / NPIX;
    int h = n / W_IN, w = n - (n / W_IN) * W_IN;
    float s = 0.f;
    for (int c = 0; c < C_IN; ++c) {
        const float* xc = x + (size_t)c * NPIX;
        const float* wc = wk + ((size_t)o * C_IN + c) * 9;
        #pragma unroll
        for (int kh = 0; kh < 3; ++kh) {
            int hh = h + kh - 1;
            if (hh < 0 || hh >= H_IN) continue;
            #pragma unroll
            for (int kw = 0; kw < 3; ++kw) {
                int ww = w + kw - 1;
                if (ww < 0 || ww >= W_IN) continue;
                s += xc[hh * W_IN + ww] * wc[kh * 3 + kw];
            }
        }
    }
    out[idx] = s;
}

extern "C" void kernel_launch(void* const* d_in, const int* in_sizes, int n_in,
                              void* d_out, int out_size, void* d_ws, size_t ws_size,
                              hipStream_t stream) {
    const float* x  = (const float*)d_in[0];
    const float* wk = (const float*)d_in[1];
    float* out = (float*)d_out;

    const size_t xp_elems = (size_t)HP * WP * C_IN;   // 13,075,456
    const size_t wb_elems = (size_t)9 * 256 * 256;    // 589,824
    const size_t need = (xp_elems + wb_elems) * 2;    // ~27.3 MB

    if (ws_size < need) {
        conv_naive<<<(C_OUT * NPIX) / 256, 256, 0, stream>>>(x, wk, out);
        return;
    }

    unsigned short* xp = (unsigned short*)d_ws;
    unsigned short* wb = xp + xp_elems;

    prep_all<<<3584 + 2304 + 113, 256, 0, stream>>>(x, wk, xp, wb);
    conv_gemm<<<196, 512, 0, stream>>>(xp, wb, out);
}